// Round 14
// baseline (937.935 us; speedup 1.0000x reference)
//
#include <hip/hip_runtime.h>
#include <math.h>

typedef short short8 __attribute__((ext_vector_type(8)));
typedef float f32x4 __attribute__((ext_vector_type(4)));

#define DEV static __device__ __forceinline__
#define NBLK 256   // blocks for bucket passes A/B

// ---- fp32 -> bf16 round-to-nearest-even; and hi/lo split -------------------
DEV unsigned int bf16h(float x) {
  unsigned int u = __float_as_uint(x);
  return (u + 0x7FFFu + ((u >> 16) & 1u)) >> 16;
}
DEV void split2(float x, unsigned int& h, unsigned int& l) {
  h = bf16h(x);
  float hf = __uint_as_float(h << 16);
  l = bf16h(x - hf);
}
DEV float b2f(unsigned int u) { return __uint_as_float(u << 16); }

// ---------------------------------------------------------------------------
// CSR build via 128-row bucket sort (cross-XCD-write-friendly), 256-way
// parallel histogram/scatter passes.
// ---------------------------------------------------------------------------
__global__ __launch_bounds__(1024) void bucketA(const int* __restrict__ dst,
                                                int* __restrict__ histG,
                                                int E, int chunk, int NB) {
  __shared__ int lh[1024];
  const int t = threadIdx.x;
  for (int i = t; i < NB; i += 1024) lh[i] = 0;
  __syncthreads();
  int s = blockIdx.x * chunk;
  int e = s + chunk; if (e > E) e = E;
  for (int i = s + t; i < e; i += 1024) atomicAdd(&lh[dst[i] >> 7], 1);
  __syncthreads();
  for (int b = t; b < NB; b += 1024) histG[b * NBLK + blockIdx.x] = lh[b];
}

// per-bucket exclusive scan over NBLK block counts + cross-bucket scan
__global__ __launch_bounds__(1024) void bucketS(int* __restrict__ histG,
                                                int* __restrict__ bucketStart,
                                                int NB) {
  __shared__ int btot[1024];
  __shared__ int wsum[16];
  const int t = threadIdx.x, lane = t & 63, wv = t >> 6;
  for (int b = wv; b < NB; b += 16) {
    int carry = 0;
#pragma unroll
    for (int c = 0; c < NBLK / 64; ++c) {
      int idx = b * NBLK + c * 64 + lane;
      int v = histG[idx];
      int x = v;
#pragma unroll
      for (int d = 1; d < 64; d <<= 1) {
        int y = __shfl_up(x, d);
        if (lane >= d) x += y;
      }
      histG[idx] = carry + (x - v);
      carry += __shfl(x, 63);
    }
    if (lane == 0) btot[b] = carry;
  }
  __syncthreads();
  int v = (t < NB) ? btot[t] : 0;
  int x = v;
#pragma unroll
  for (int d = 1; d < 64; d <<= 1) {
    int y = __shfl_up(x, d);
    if (lane >= d) x += y;
  }
  if (lane == 63) wsum[wv] = x;
  __syncthreads();
  if (wv == 0) {
    int y = (lane < 16) ? wsum[lane] : 0;
#pragma unroll
    for (int d = 1; d < 16; d <<= 1) {
      int z = __shfl_up(y, d);
      if (lane >= d) y += z;
    }
    if (lane < 16) wsum[lane] = y;
  }
  __syncthreads();
  int wbase = (wv > 0) ? wsum[wv - 1] : 0;
  int incl = wbase + x;
  if (t < NB) bucketStart[t] = incl - v;
  if (t == NB - 1) bucketStart[NB] = incl;
}

__global__ __launch_bounds__(1024) void bucketB(const int* __restrict__ src,
                                                const int* __restrict__ dstA,
                                                const int* __restrict__ histG,
                                                const int* __restrict__ bucketStart,
                                                int2* __restrict__ pairs,
                                                int E, int chunk, int NB) {
  __shared__ int lbase[1024];
  __shared__ int lcnt[1024];
  const int t = threadIdx.x;
  for (int i = t; i < NB; i += 1024) {
    lbase[i] = bucketStart[i] + histG[i * NBLK + blockIdx.x];
    lcnt[i] = 0;
  }
  __syncthreads();
  int s = blockIdx.x * chunk;
  int e = s + chunk; if (e > E) e = E;
  for (int i = s + t; i < e; i += 1024) {
    int d = dstA[i];
    int b = d >> 7;
    int r = atomicAdd(&lcnt[b], 1);
    pairs[lbase[b] + r] = make_int2(src[i], d);
  }
}

__global__ __launch_bounds__(256) void bucketC(const int2* __restrict__ pairs,
                                               const int* __restrict__ bucketStart,
                                               int* __restrict__ rowptr,
                                               int* __restrict__ colidx,
                                               float* __restrict__ n1,
                                               float* __restrict__ n2,
                                               int N, int E) {
  __shared__ int degs[128];
  __shared__ int incl[128];
  __shared__ int cur[128];
  const int t = threadIdx.x, lane = t & 63;
  const int b = blockIdx.x;
  const int lo = b << 7;
  const int s0 = bucketStart[b], s1 = bucketStart[b + 1];
  if (t < 128) degs[t] = 0;
  __syncthreads();
  for (int i = s0 + t; i < s1; i += 256) atomicAdd(&degs[pairs[i].y - lo], 1);
  __syncthreads();
  int d = 0, x = 0;
  if (t < 128) {
    d = degs[t];
    x = d;
#pragma unroll
    for (int dd = 1; dd < 64; dd <<= 1) {
      int y = __shfl_up(x, dd);
      if (lane >= dd) x += y;
    }
    incl[t] = x;
  }
  __syncthreads();
  if (t >= 64 && t < 128) incl[t] += incl[63];
  __syncthreads();
  if (t < 128) {
    int excl = incl[t] - d;
    int row = lo + t;
    if (row < N) {
      rowptr[row] = s0 + excl;
      int dd2 = d < 1 ? 1 : d;
      float fd = (float)dd2;
      float r = 1.0f / sqrtf(fd);
      n1[row] = r;
      n2[row] = r / fd;
    }
    cur[t] = excl;
  }
  __syncthreads();
  for (int i = s0 + t; i < s1; i += 256) {
    int2 p = pairs[i];
    int off = atomicAdd(&cur[p.y - lo], 1);
    colidx[s0 + off] = p.x;
  }
  if (b == 0 && t == 0) rowptr[N] = E;
}

// ---------------------------------------------------------------------------
// Weight prep, single launch (transposed [C][K] + hi/lo split)
// ---------------------------------------------------------------------------
__global__ __launch_bounds__(256) void prep_all(
    const float* __restrict__ encW, const float* __restrict__ W1,
    const float* __restrict__ W2, unsigned short* __restrict__ encWh,
    unsigned short* __restrict__ encWl, unsigned short* __restrict__ W1th,
    unsigned short* __restrict__ W1tl, unsigned short* __restrict__ W2th,
    unsigned short* __restrict__ W2tl, int L) {
  int t = blockIdx.x * 256 + threadIdx.x;
  const int n1e = 16384;
  const int n2e = n1e + L * 32768;
  const int n3e = n2e + L * 16384;
  unsigned int h, l;
  if (t < n1e) {
    int c = t >> 7, k = t & 127;
    split2(encW[k * 128 + c], h, l);
    encWh[t] = (unsigned short)h; encWl[t] = (unsigned short)l;
  } else if (t < n2e) {
    int u = t - n1e;
    int ll = u >> 15, w = u & 32767;
    int c = w >> 8, k = w & 255;
    split2(W1[(size_t)ll * 32768 + k * 128 + c], h, l);
    W1th[u] = (unsigned short)h; W1tl[u] = (unsigned short)l;
  } else if (t < n3e) {
    int u = t - n2e;
    int ll = u >> 14, w = u & 16383;
    int c = w >> 7, k = w & 127;
    split2(W2[(size_t)ll * 16384 + k * 128 + c], h, l);
    W2th[u] = (unsigned short)h; W2tl[u] = (unsigned short)l;
  }
}

// ---------------------------------------------------------------------------
// Fused layer kernel, BK=64, 48KB LDS -> 3 blocks/CU.
// KIND 0 (encoder): h = bf16(fp32A @ W1 + b1)
// KIND 1 (layer):   prologue: agg tile gather (8 waves x 16 rows, 8-wide
//   batched; block == CSR bucket; write coalesced to aggb, read back L2-hot);
//   z = relu([h|agg]@W1+b1); out = h + relu(z@W2+b2).
// h double-buffered across layers (gather reads other blocks' prev-h).
// ---------------------------------------------------------------------------
template <int KIND>
__global__ __launch_bounds__(512, 6) void sage_mm(
    const float* __restrict__ Af, const unsigned short* __restrict__ Ab,
    unsigned short* __restrict__ aggb,
    const int* __restrict__ rowptr, const int* __restrict__ colidx,
    const float* __restrict__ n1f, const float* __restrict__ n2f,
    const unsigned short* __restrict__ W1h, const unsigned short* __restrict__ W1l,
    const unsigned short* __restrict__ W2h, const unsigned short* __restrict__ W2l,
    const float* __restrict__ b1, const float* __restrict__ b2,
    unsigned short* __restrict__ outb, int M) {
  __shared__ unsigned short lds[128 * 64 * 3];   // As | WsH | WsL (48KB)
  unsigned short* As = lds;
  unsigned short* WsH = lds + 128 * 64;
  unsigned short* WsL = lds + 128 * 64 * 2;

  const int t = threadIdx.x;
  const int lane = t & 63;
  const int w = t >> 6;
  const int rl = lane & 15, g = lane >> 4;
  const int rbase = (w >> 2) * 64;
  const int cbase = (w & 3) * 32;
  const int rowbase = blockIdx.x * 128;

  // ---- KIND 1 prologue: gather agg tile for this block's 128 rows ---------
  if (KIND == 1) {
    const unsigned int* hprev = (const unsigned int*)Ab;  // 64 uints/row
    int wrow0 = w * 16;
#pragma unroll 1
    for (int i = 0; i < 16; ++i) {
      int row = rowbase + wrow0 + i;
      if (row >= M) break;
      int s = rowptr[row], e = rowptr[row + 1];
      float ax[4] = {0.f, 0.f, 0.f, 0.f};
      float ay[4] = {0.f, 0.f, 0.f, 0.f};
      for (int ii = s; ii < e; ii += 8) {
        int c[8];
#pragma unroll
        for (int j = 0; j < 8; ++j) {
          int idx = ii + j;
          c[j] = colidx[idx < e ? idx : e - 1];
        }
        float sc[8];
#pragma unroll
        for (int j = 0; j < 8; ++j) sc[j] = (ii + j < e) ? n1f[c[j]] : 0.f;
        unsigned int v[8];
#pragma unroll
        for (int j = 0; j < 8; ++j) v[j] = hprev[(size_t)c[j] * 64 + lane];
#pragma unroll
        for (int j = 0; j < 8; ++j) {
          ax[j & 3] = fmaf(b2f(v[j] & 0xffffu), sc[j], ax[j & 3]);
          ay[j & 3] = fmaf(__uint_as_float(v[j] & 0xffff0000u), sc[j], ay[j & 3]);
        }
      }
      float m = n2f[row];
      float axs = ((ax[0] + ax[1]) + (ax[2] + ax[3])) * m;
      float ays = ((ay[0] + ay[1]) + (ay[2] + ay[3])) * m;
      ((unsigned int*)aggb)[(size_t)row * 64 + lane] =
          bf16h(axs) | (bf16h(ays) << 16);
    }
  }

  auto stageW = [&](const unsigned short* sh, const unsigned short* sl, int ldk,
                    int k0) {
#pragma unroll
    for (int j = 0; j < 2; ++j) {
      int ch = t * 2 + j;
      int c = ch >> 3, cc = ch & 7;
      int off = c * 128 + ((cc ^ (c & 7)) << 4);
      *(int4*)((char*)WsH + off) = *(const int4*)(sh + (size_t)c * ldk + k0 + cc * 8);
      *(int4*)((char*)WsL + off) = *(const int4*)(sl + (size_t)c * ldk + k0 + cc * 8);
    }
  };

  auto stageAf = [&](const float* __restrict__ src, int k0) {
    int r = t >> 2, kc = (t & 3) * 16;
    int grow = rowbase + r;
    const float4* s = (const float4*)(src + (size_t)grow * 128 + k0 + kc);
#pragma unroll
    for (int j = 0; j < 4; ++j) {
      float4 v = make_float4(0.f, 0.f, 0.f, 0.f);
      if (grow < M) v = s[j];
      unsigned int h0 = bf16h(v.x), h1 = bf16h(v.y);
      unsigned int h2 = bf16h(v.z), h3 = bf16h(v.w);
      int k = kc + j * 4;
      int off = r * 128 + (((k >> 3) ^ (r & 7)) << 4) + (k & 7) * 2;
      *(int2*)((char*)As + off) =
          make_int2((int)(h0 | (h1 << 16)), (int)(h2 | (h3 << 16)));
    }
  };

  auto stageAb = [&](const unsigned short* __restrict__ src, int k0) {
    int r = t >> 2, kc = (t & 3) * 16;
    int grow = rowbase + r;
    const int4* s = (const int4*)(src + (size_t)grow * 128 + k0 + kc);
#pragma unroll
    for (int j = 0; j < 2; ++j) {
      int4 v = make_int4(0, 0, 0, 0);
      if (grow < M) v = s[j];
      int ch = (kc >> 3) + j;
      int off = r * 128 + ((ch ^ (r & 7)) << 4);
      *(int4*)((char*)As + off) = v;
    }
  };

  f32x4 acc[4][2];
  auto zacc = [&]() {
#pragma unroll
    for (int i = 0; i < 4; ++i)
#pragma unroll
      for (int j = 0; j < 2; ++j) {
        f32x4 z = {0.f, 0.f, 0.f, 0.f};
        acc[i][j] = z;
      }
  };

  auto kloop = [&]() {
#pragma unroll
    for (int ks = 0; ks < 2; ++ks) {
      short8 aH[4], bH[2], bL[2];
#pragma unroll
      for (int fr = 0; fr < 4; ++fr) {
        int row = rbase + fr * 16 + rl;
        int off = row * 128 + (((ks * 4 + g) ^ (row & 7)) << 4);
        aH[fr] = *(const short8*)((const char*)As + off);
      }
#pragma unroll
      for (int fc = 0; fc < 2; ++fc) {
        int col = cbase + fc * 16 + rl;
        int off = col * 128 + (((ks * 4 + g) ^ (col & 7)) << 4);
        bH[fc] = *(const short8*)((const char*)WsH + off);
        bL[fc] = *(const short8*)((const char*)WsL + off);
      }
#pragma unroll
      for (int fr = 0; fr < 4; ++fr)
#pragma unroll
        for (int fc = 0; fc < 2; ++fc) {
          acc[fr][fc] = __builtin_amdgcn_mfma_f32_16x16x32_bf16(
              aH[fr], bH[fc], acc[fr][fc], 0, 0, 0);
          acc[fr][fc] = __builtin_amdgcn_mfma_f32_16x16x32_bf16(
              aH[fr], bL[fc], acc[fr][fc], 0, 0, 0);
        }
    }
  };

  auto zstage = [&](int c0) {
#pragma unroll
    for (int fc = 0; fc < 2; ++fc) {
      int col = cbase + fc * 16 + rl;
      unsigned int lc = (unsigned int)(col - c0);
      if (lc < 64u) {
        float bb = b1[col];
#pragma unroll
        for (int fr = 0; fr < 4; ++fr)
#pragma unroll
          for (int q = 0; q < 4; ++q) {
            int row = rbase + fr * 16 + g * 4 + q;
            float z = fmaxf(acc[fr][fc][q] + bb, 0.f);
            int off = row * 128 + (((lc >> 3) ^ (row & 7)) << 4) + (lc & 7) * 2;
            *(unsigned short*)((char*)As + off) = (unsigned short)bf16h(z);
          }
      }
    }
  };

  zacc();
  if (KIND == 0) {
    stageAf(Af, 0);  stageW(W1h, W1l, 128, 0);
    __syncthreads(); kloop(); __syncthreads();
    stageAf(Af, 64); stageW(W1h, W1l, 128, 64);
    __syncthreads(); kloop();
  } else {
    stageAb(Ab, 0);   stageW(W1h, W1l, 256, 0);
    __syncthreads(); kloop(); __syncthreads();
    stageAb(Ab, 64);  stageW(W1h, W1l, 256, 64);
    __syncthreads(); kloop(); __syncthreads();
    // agg tile written by this block's waves; >=2 barriers since -> visible
    stageAb(aggb, 0);  stageW(W1h, W1l, 256, 128);
    __syncthreads(); kloop(); __syncthreads();
    stageAb(aggb, 64); stageW(W1h, W1l, 256, 192);
    __syncthreads(); kloop(); __syncthreads();

    zstage(0); stageW(W2h, W2l, 128, 0);
    f32x4 acc1[4][2];
#pragma unroll
    for (int i = 0; i < 4; ++i)
#pragma unroll
      for (int j = 0; j < 2; ++j) acc1[i][j] = acc[i][j];
    zacc();
    __syncthreads(); kloop(); __syncthreads();
#pragma unroll
    for (int i = 0; i < 4; ++i)
#pragma unroll
      for (int j = 0; j < 2; ++j) {
        f32x4 tmp = acc[i][j];
        acc[i][j] = acc1[i][j];
        acc1[i][j] = tmp;
      }
    zstage(64); stageW(W2h, W2l, 128, 64);
#pragma unroll
    for (int i = 0; i < 4; ++i)
#pragma unroll
      for (int j = 0; j < 2; ++j) acc[i][j] = acc1[i][j];
    __syncthreads(); kloop();
  }

  // ---- epilogue: stage C in LDS -> coalesced 16B/lane writes ---------------
  __syncthreads();
  unsigned short* Cs = lds;  // 32KB
  const float* bias = (KIND == 0) ? b1 : b2;
#pragma unroll
  for (int fc = 0; fc < 2; ++fc) {
    int col = cbase + fc * 16 + rl;
    float bb = bias[col];
#pragma unroll
    for (int fr = 0; fr < 4; ++fr)
#pragma unroll
      for (int q = 0; q < 4; ++q) {
        int row = rbase + fr * 16 + g * 4 + q;
        float val = acc[fr][fc][q] + bb;
        if (KIND == 1) val = fmaxf(val, 0.f);
        Cs[row * 128 + col] = (unsigned short)bf16h(val);
      }
  }
  __syncthreads();
#pragma unroll
  for (int p = 0; p < 4; ++p) {
    int bo = p * 8192 + t * 16;
    int row = bo >> 8;
    int grow = rowbase + row;
    if (grow >= M) continue;
    int4 z4 = *(const int4*)((const char*)Cs + bo);
    if (KIND == 1) {
      int4 a4 = *(const int4*)((const char*)Ab + (size_t)grow * 256 + (bo & 255));
      int* zp = (int*)&z4;
      const int* ap = (const int*)&a4;
#pragma unroll
      for (int u = 0; u < 4; ++u) {
        unsigned int za = (unsigned int)zp[u], aa = (unsigned int)ap[u];
        float vlo = b2f(za & 0xffffu) + b2f(aa & 0xffffu);
        float vhi = __uint_as_float(za & 0xffff0000u) +
                    __uint_as_float(aa & 0xffff0000u);
        zp[u] = (int)(bf16h(vlo) | (bf16h(vhi) << 16));
      }
    }
    *(int4*)((char*)outb + (size_t)grow * 256 + (bo & 255)) = z4;
  }
}

// ---------------------------------------------------------------------------
// Pooling + readout (h in bf16)
// ---------------------------------------------------------------------------
__global__ __launch_bounds__(256) void pool_partial(
    const unsigned short* __restrict__ h, float* __restrict__ partial, int N) {
  int col = threadIdx.x & 127;
  int stream = blockIdx.x * 2 + (threadIdx.x >> 7);
  float s = 0.f;
  for (int r = stream; r < N; r += 512)
    s += b2f((unsigned int)h[(size_t)r * 128 + col]);
  partial[stream * 128 + col] = s;
}

__global__ __launch_bounds__(256) void readout_kernel(
    const float* __restrict__ partial, const float* __restrict__ rW1,
    const float* __restrict__ rb1, const float* __restrict__ rW2,
    const float* __restrict__ rb2, const float* __restrict__ rW3,
    const float* __restrict__ rb3, float* __restrict__ outp, int N) {
  __shared__ float pooled[128];
  __shared__ float x1[64];
  __shared__ float x2[32];
  int t = threadIdx.x;
  if (t < 128) {
    float s = 0.f;
    for (int i = 0; i < 512; ++i) s += partial[i * 128 + t];
    pooled[t] = s / (float)N;
  }
  __syncthreads();
  if (t < 64) {
    float s = rb1[t];
    for (int k = 0; k < 128; ++k) s = fmaf(pooled[k], rW1[k * 64 + t], s);
    x1[t] = fmaxf(s, 0.f);
  }
  __syncthreads();
  if (t < 32) {
    float s = rb2[t];
    for (int k = 0; k < 64; ++k) s = fmaf(x1[k], rW2[k * 32 + t], s);
    x2[t] = fmaxf(s, 0.f);
  }
  __syncthreads();
  if (t < 10) {
    float s = rb3[t];
    for (int k = 0; k < 32; ++k) s = fmaf(x2[k], rW3[k * 10 + t], s);
    outp[t] = s;
  }
}

extern "C" void kernel_launch(void* const* d_in, const int* in_sizes, int n_in,
                              void* d_out, int out_size, void* d_ws, size_t ws_size,
                              hipStream_t stream) {
  const float* h_in  = (const float*)d_in[0];
  const int*   src   = (const int*)d_in[1];
  const int*   dst   = (const int*)d_in[2];
  const float* enc_W = (const float*)d_in[3];
  const float* enc_b = (const float*)d_in[4];
  const float* W1    = (const float*)d_in[5];
  const float* b1    = (const float*)d_in[6];
  const float* W2    = (const float*)d_in[7];
  const float* b2    = (const float*)d_in[8];
  const float* rW1   = (const float*)d_in[9];
  const float* rb1   = (const float*)d_in[10];
  const float* rW2   = (const float*)d_in[11];
  const float* rb2   = (const float*)d_in[12];
  const float* rW3   = (const float*)d_in[13];
  const float* rb3   = (const float*)d_in[14];

  const int N = in_sizes[0] / 128;
  const int E = in_sizes[1];
  const int L = in_sizes[6] / 128;
  const int NB = (N + 127) >> 7;
  const int chunk = (E + NBLK - 1) / NBLK;

  char* ws = (char*)d_ws;
  size_t off = 0;
  auto alloc = [&](size_t bytes) {
    char* p = ws + off;
    off = (off + bytes + 511) & ~(size_t)511;
    return p;
  };
  unsigned short* hA  = (unsigned short*)alloc((size_t)N * 128 * 2);
  unsigned short* hB  = (unsigned short*)alloc((size_t)N * 128 * 2);
  unsigned short* agg = (unsigned short*)alloc((size_t)N * 128 * 2);
  int* rowptr     = (int*)alloc((size_t)(N + 1) * 4);
  int* colidx     = (int*)alloc((size_t)E * 4);
  float* n1       = (float*)alloc((size_t)N * 4);
  float* n2       = (float*)alloc((size_t)N * 4);
  int* histG      = (int*)alloc((size_t)NB * NBLK * 4);
  int* bucketStart= (int*)alloc((size_t)(NB + 1) * 4);
  float* partial  = (float*)alloc((size_t)512 * 128 * 4);
  unsigned short* encWh = (unsigned short*)alloc(16384 * 2);
  unsigned short* encWl = (unsigned short*)alloc(16384 * 2);
  unsigned short* W1th  = (unsigned short*)alloc((size_t)L * 32768 * 2);
  unsigned short* W1tl  = (unsigned short*)alloc((size_t)L * 32768 * 2);
  unsigned short* W2th  = (unsigned short*)alloc((size_t)L * 16384 * 2);
  unsigned short* W2tl  = (unsigned short*)alloc((size_t)L * 16384 * 2);
  int2* pairs = (int2*)alloc((size_t)E * 8);   // CSR scratch (dead after bucketC)
  (void)ws_size; (void)n_in; (void)out_size;

  {
    int tot = 16384 + L * 32768 + L * 16384;
    prep_all<<<(tot + 255) / 256, 256, 0, stream>>>(
        enc_W, W1, W2, encWh, encWl, W1th, W1tl, W2th, W2tl, L);
  }

  bucketA<<<NBLK, 1024, 0, stream>>>(dst, histG, E, chunk, NB);
  bucketS<<<1, 1024, 0, stream>>>(histG, bucketStart, NB);
  bucketB<<<NBLK, 1024, 0, stream>>>(src, dst, histG, bucketStart, pairs, E,
                                     chunk, NB);
  bucketC<<<NB, 256, 0, stream>>>(pairs, bucketStart, rowptr, colidx, n1, n2, N, E);

  const int gblocks = (N + 127) / 128;
  sage_mm<0><<<gblocks, 512, 0, stream>>>(
      h_in, nullptr, nullptr, nullptr, nullptr, nullptr, nullptr,
      encWh, encWl, nullptr, nullptr, enc_b, nullptr, hA, N);
  const unsigned short* hin = hA;
  unsigned short* hout = hB;
  for (int l = 0; l < L; ++l) {
    sage_mm<1><<<gblocks, 512, 0, stream>>>(
        nullptr, hin, agg, rowptr, colidx, n1, n2,
        W1th + (size_t)l * 32768, W1tl + (size_t)l * 32768,
        W2th + (size_t)l * 16384, W2tl + (size_t)l * 16384,
        b1 + l * 128, b2 + l * 128, hout, N);
    const unsigned short* tmp = hin;
    hin = hout;
    hout = (unsigned short*)tmp;
  }
  pool_partial<<<256, 256, 0, stream>>>(hin, partial, N);
  readout_kernel<<<1, 256, 0, stream>>>(partial, rW1, rb1, rW2, rb2, rW3, rb3,
                                        (float*)d_out, N);
}

// Round 15
// 715.393 us; speedup vs baseline: 1.3111x; 1.3111x over previous
//
#include <hip/hip_runtime.h>
#include <math.h>

typedef short short8 __attribute__((ext_vector_type(8)));
typedef float f32x4 __attribute__((ext_vector_type(4)));

#define DEV static __device__ __forceinline__
#define NBLK 256   // blocks for bucket passes A/B

// ---- fp32 -> bf16 round-to-nearest-even; and hi/lo split -------------------
DEV unsigned int bf16h(float x) {
  unsigned int u = __float_as_uint(x);
  return (u + 0x7FFFu + ((u >> 16) & 1u)) >> 16;
}
DEV void split2(float x, unsigned int& h, unsigned int& l) {
  h = bf16h(x);
  float hf = __uint_as_float(h << 16);
  l = bf16h(x - hf);
}
DEV float b2f(unsigned int u) { return __uint_as_float(u << 16); }

// dest index (ushort units) inside a weight LDS-image: element (c,k) of a
// [128 cols][K] tile; K-subtile s=k>>6 is a 16KB image laid out exactly as
// the LDS tile (chunk cc of col c at byte c*128 + ((cc^(c&7))<<4)).
DEV int imgidx(int c, int k) {
  int s = k >> 6, kk = k & 63, cc = kk >> 3;
  return s * 8192 + c * 64 + ((cc ^ (c & 7)) << 3) + (kk & 7);
}

// ---------------------------------------------------------------------------
// CSR build via 128-row bucket sort (cross-XCD-write-friendly).
// ---------------------------------------------------------------------------
__global__ __launch_bounds__(1024) void bucketA(const int* __restrict__ dst,
                                                int* __restrict__ histG,
                                                int E, int chunk, int NB) {
  __shared__ int lh[1024];
  const int t = threadIdx.x;
  for (int i = t; i < NB; i += 1024) lh[i] = 0;
  __syncthreads();
  int s = blockIdx.x * chunk;
  int e = s + chunk; if (e > E) e = E;
  for (int i = s + t; i < e; i += 1024) atomicAdd(&lh[dst[i] >> 7], 1);
  __syncthreads();
  for (int b = t; b < NB; b += 1024) histG[b * NBLK + blockIdx.x] = lh[b];
}

__global__ __launch_bounds__(1024) void bucketS(int* __restrict__ histG,
                                                int* __restrict__ bucketStart,
                                                int NB) {
  __shared__ int btot[1024];
  __shared__ int wsum[16];
  const int t = threadIdx.x, lane = t & 63, wv = t >> 6;
  for (int b = wv; b < NB; b += 16) {
    int carry = 0;
#pragma unroll
    for (int c = 0; c < NBLK / 64; ++c) {
      int idx = b * NBLK + c * 64 + lane;
      int v = histG[idx];
      int x = v;
#pragma unroll
      for (int d = 1; d < 64; d <<= 1) {
        int y = __shfl_up(x, d);
        if (lane >= d) x += y;
      }
      histG[idx] = carry + (x - v);
      carry += __shfl(x, 63);
    }
    if (lane == 0) btot[b] = carry;
  }
  __syncthreads();
  int v = (t < NB) ? btot[t] : 0;
  int x = v;
#pragma unroll
  for (int d = 1; d < 64; d <<= 1) {
    int y = __shfl_up(x, d);
    if (lane >= d) x += y;
  }
  if (lane == 63) wsum[wv] = x;
  __syncthreads();
  if (wv == 0) {
    int y = (lane < 16) ? wsum[lane] : 0;
#pragma unroll
    for (int d = 1; d < 16; d <<= 1) {
      int z = __shfl_up(y, d);
      if (lane >= d) y += z;
    }
    if (lane < 16) wsum[lane] = y;
  }
  __syncthreads();
  int wbase = (wv > 0) ? wsum[wv - 1] : 0;
  int incl = wbase + x;
  if (t < NB) bucketStart[t] = incl - v;
  if (t == NB - 1) bucketStart[NB] = incl;
}

__global__ __launch_bounds__(1024) void bucketB(const int* __restrict__ src,
                                                const int* __restrict__ dstA,
                                                const int* __restrict__ histG,
                                                const int* __restrict__ bucketStart,
                                                int2* __restrict__ pairs,
                                                int E, int chunk, int NB) {
  __shared__ int lbase[1024];
  __shared__ int lcnt[1024];
  const int t = threadIdx.x;
  for (int i = t; i < NB; i += 1024) {
    lbase[i] = bucketStart[i] + histG[i * NBLK + blockIdx.x];
    lcnt[i] = 0;
  }
  __syncthreads();
  int s = blockIdx.x * chunk;
  int e = s + chunk; if (e > E) e = E;
  for (int i = s + t; i < e; i += 1024) {
    int d = dstA[i];
    int b = d >> 7;
    int r = atomicAdd(&lcnt[b], 1);
    pairs[lbase[b] + r] = make_int2(src[i], d);
  }
}

__global__ __launch_bounds__(256) void bucketC(const int2* __restrict__ pairs,
                                               const int* __restrict__ bucketStart,
                                               int* __restrict__ rowptr,
                                               int* __restrict__ colidx,
                                               float* __restrict__ n1,
                                               float* __restrict__ n2,
                                               int N, int E) {
  __shared__ int degs[128];
  __shared__ int incl[128];
  __shared__ int cur[128];
  const int t = threadIdx.x, lane = t & 63;
  const int b = blockIdx.x;
  const int lo = b << 7;
  const int s0 = bucketStart[b], s1 = bucketStart[b + 1];
  if (t < 128) degs[t] = 0;
  __syncthreads();
  for (int i = s0 + t; i < s1; i += 256) atomicAdd(&degs[pairs[i].y - lo], 1);
  __syncthreads();
  int d = 0, x = 0;
  if (t < 128) {
    d = degs[t];
    x = d;
#pragma unroll
    for (int dd = 1; dd < 64; dd <<= 1) {
      int y = __shfl_up(x, dd);
      if (lane >= dd) x += y;
    }
    incl[t] = x;
  }
  __syncthreads();
  if (t >= 64 && t < 128) incl[t] += incl[63];
  __syncthreads();
  if (t < 128) {
    int excl = incl[t] - d;
    int row = lo + t;
    if (row < N) {
      rowptr[row] = s0 + excl;
      int dd2 = d < 1 ? 1 : d;
      float fd = (float)dd2;
      float r = 1.0f / sqrtf(fd);
      n1[row] = r;
      n2[row] = r / fd;
    }
    cur[t] = excl;
  }
  __syncthreads();
  for (int i = s0 + t; i < s1; i += 256) {
    int2 p = pairs[i];
    int off = atomicAdd(&cur[p.y - lo], 1);
    colidx[s0 + off] = p.x;
  }
  if (b == 0 && t == 0) rowptr[N] = E;
}

// ---------------------------------------------------------------------------
// agg[i] = bf16( ( sum_e h[col]*n1[col] ) * n2[i] )    h: bf16 rows, 256B
// ---------------------------------------------------------------------------
__global__ __launch_bounds__(256) void agg_kernel(
    const unsigned short* __restrict__ h, const int* __restrict__ rowptr,
    const int* __restrict__ colidx, const float* __restrict__ n1,
    const float* __restrict__ n2, unsigned short* __restrict__ agg, int N) {
  int wid = (blockIdx.x * 256 + threadIdx.x) >> 6;
  int lane = threadIdx.x & 63;
  if (wid >= N) return;
  int s = rowptr[wid], e = rowptr[wid + 1];
  const unsigned int* h2 = (const unsigned int*)h;  // 2 bf16 / uint, 64/row
  float ax[4] = {0.f, 0.f, 0.f, 0.f};
  float ay[4] = {0.f, 0.f, 0.f, 0.f};
  for (int i = s; i < e; i += 8) {
    int c[8];
#pragma unroll
    for (int j = 0; j < 8; ++j) {
      int idx = i + j;
      c[j] = colidx[idx < e ? idx : e - 1];
    }
    float sc[8];
#pragma unroll
    for (int j = 0; j < 8; ++j) sc[j] = (i + j < e) ? n1[c[j]] : 0.f;
    unsigned int v[8];
#pragma unroll
    for (int j = 0; j < 8; ++j) v[j] = h2[(size_t)c[j] * 64 + lane];
#pragma unroll
    for (int j = 0; j < 8; ++j) {
      ax[j & 3] = fmaf(b2f(v[j] & 0xffffu), sc[j], ax[j & 3]);
      ay[j & 3] = fmaf(__uint_as_float(v[j] & 0xffff0000u), sc[j], ay[j & 3]);
    }
  }
  float m = n2[wid];
  float axs = ((ax[0] + ax[1]) + (ax[2] + ax[3])) * m;
  float ays = ((ay[0] + ay[1]) + (ay[2] + ay[3])) * m;
  ((unsigned int*)agg)[(size_t)wid * 64 + lane] = bf16h(axs) | (bf16h(ays) << 16);
}

// ---------------------------------------------------------------------------
// Weight prep, single launch: transposed + hi/lo split + pre-swizzled into
// LDS-image layout (so sage_mm can stage W with global_load_lds, linear dest).
// ---------------------------------------------------------------------------
__global__ __launch_bounds__(256) void prep_all(
    const float* __restrict__ encW, const float* __restrict__ W1,
    const float* __restrict__ W2, unsigned short* __restrict__ encWh,
    unsigned short* __restrict__ encWl, unsigned short* __restrict__ W1th,
    unsigned short* __restrict__ W1tl, unsigned short* __restrict__ W2th,
    unsigned short* __restrict__ W2tl, int L) {
  int t = blockIdx.x * 256 + threadIdx.x;
  const int n1e = 16384;
  const int n2e = n1e + L * 32768;
  const int n3e = n2e + L * 16384;
  unsigned int h, l;
  if (t < n1e) {
    int c = t >> 7, k = t & 127;
    split2(encW[k * 128 + c], h, l);
    int di = imgidx(c, k);
    encWh[di] = (unsigned short)h; encWl[di] = (unsigned short)l;
  } else if (t < n2e) {
    int u = t - n1e;
    int ll = u >> 15, w = u & 32767;
    int c = w >> 8, k = w & 255;
    split2(W1[(size_t)ll * 32768 + k * 128 + c], h, l);
    int di = ll * 32768 + imgidx(c, k);
    W1th[di] = (unsigned short)h; W1tl[di] = (unsigned short)l;
  } else if (t < n3e) {
    int u = t - n2e;
    int ll = u >> 14, w = u & 16383;
    int c = w >> 7, k = w & 127;
    split2(W2[(size_t)ll * 16384 + k * 128 + c], h, l);
    int di = ll * 16384 + imgidx(c, k);
    W2th[di] = (unsigned short)h; W2tl[di] = (unsigned short)l;
  }
}

// ---------------------------------------------------------------------------
// Fused MFMA kernel, BK=64, 48KB LDS -> 3 blocks/CU.
// h/agg in bf16; W hi/lo split, staged via async global_load_lds from
// pre-swizzled images (linear LDS dest). Coalesced LDS-staged epilogue.
// ---------------------------------------------------------------------------
template <int KIND>
__global__ __launch_bounds__(512, 6) void sage_mm(
    const float* __restrict__ Af, const unsigned short* __restrict__ Ab,
    const unsigned short* __restrict__ A2b,
    const unsigned short* __restrict__ W1h, const unsigned short* __restrict__ W1l,
    const unsigned short* __restrict__ W2h, const unsigned short* __restrict__ W2l,
    const float* __restrict__ b1, const float* __restrict__ b2,
    unsigned short* __restrict__ outb, int M) {
  __shared__ unsigned short lds[128 * 64 * 3];   // As | WsH | WsL (48KB)
  unsigned short* As = lds;
  unsigned short* WsH = lds + 128 * 64;
  unsigned short* WsL = lds + 128 * 64 * 2;

  const int t = threadIdx.x;
  const int lane = t & 63;
  const int w = t >> 6;
  const int rl = lane & 15, g = lane >> 4;
  const int rbase = (w >> 2) * 64;
  const int cbase = (w & 3) * 32;
  const int rowbase = blockIdx.x * 128;

  // async stage one 16KB pre-swizzled W image pair (subtile sub)
  auto stageW = [&](const unsigned short* imgh, const unsigned short* imgl,
                    int sub) {
    const char* gh = (const char*)(imgh + sub * 8192);
    const char* gl = (const char*)(imgl + sub * 8192);
    int o = w * 2048 + lane * 16;
#if defined(__has_builtin) && __has_builtin(__builtin_amdgcn_global_load_lds)
    __builtin_amdgcn_global_load_lds(gh + o, (char*)WsH + w * 2048, 16, 0, 0);
    __builtin_amdgcn_global_load_lds(gh + o + 1024, (char*)WsH + w * 2048 + 1024,
                                     16, 0, 0);
    __builtin_amdgcn_global_load_lds(gl + o, (char*)WsL + w * 2048, 16, 0, 0);
    __builtin_amdgcn_global_load_lds(gl + o + 1024, (char*)WsL + w * 2048 + 1024,
                                     16, 0, 0);
#else
    *(int4*)((char*)WsH + o) = *(const int4*)(gh + o);
    *(int4*)((char*)WsH + o + 1024) = *(const int4*)(gh + o + 1024);
    *(int4*)((char*)WsL + o) = *(const int4*)(gl + o);
    *(int4*)((char*)WsL + o + 1024) = *(const int4*)(gl + o + 1024);
#endif
  };

  auto stageAf = [&](const float* __restrict__ src, int k0) {
    int r = t >> 2, kc = (t & 3) * 16;
    int grow = rowbase + r;
    const float4* s = (const float4*)(src + (size_t)grow * 128 + k0 + kc);
#pragma unroll
    for (int j = 0; j < 4; ++j) {
      float4 v = make_float4(0.f, 0.f, 0.f, 0.f);
      if (grow < M) v = s[j];
      unsigned int h0 = bf16h(v.x), h1 = bf16h(v.y);
      unsigned int h2 = bf16h(v.z), h3 = bf16h(v.w);
      int k = kc + j * 4;
      int off = r * 128 + (((k >> 3) ^ (r & 7)) << 4) + (k & 7) * 2;
      *(int2*)((char*)As + off) =
          make_int2((int)(h0 | (h1 << 16)), (int)(h2 | (h3 << 16)));
    }
  };

  auto stageAb = [&](const unsigned short* __restrict__ src, int k0) {
    int r = t >> 2, kc = (t & 3) * 16;
    int grow = rowbase + r;
    const int4* s = (const int4*)(src + (size_t)grow * 128 + k0 + kc);
#pragma unroll
    for (int j = 0; j < 2; ++j) {
      int4 v = make_int4(0, 0, 0, 0);
      if (grow < M) v = s[j];
      int ch = (kc >> 3) + j;
      int off = r * 128 + ((ch ^ (r & 7)) << 4);
      *(int4*)((char*)As + off) = v;
    }
  };

  f32x4 acc[4][2];
  auto zacc = [&]() {
#pragma unroll
    for (int i = 0; i < 4; ++i)
#pragma unroll
      for (int j = 0; j < 2; ++j) {
        f32x4 z = {0.f, 0.f, 0.f, 0.f};
        acc[i][j] = z;
      }
  };

  auto kloop = [&]() {
#pragma unroll
    for (int ks = 0; ks < 2; ++ks) {
      short8 aH[4], bH[2], bL[2];
#pragma unroll
      for (int fr = 0; fr < 4; ++fr) {
        int row = rbase + fr * 16 + rl;
        int off = row * 128 + (((ks * 4 + g) ^ (row & 7)) << 4);
        aH[fr] = *(const short8*)((const char*)As + off);
      }
#pragma unroll
      for (int fc = 0; fc < 2; ++fc) {
        int col = cbase + fc * 16 + rl;
        int off = col * 128 + (((ks * 4 + g) ^ (col & 7)) << 4);
        bH[fc] = *(const short8*)((const char*)WsH + off);
        bL[fc] = *(const short8*)((const char*)WsL + off);
      }
#pragma unroll
      for (int fr = 0; fr < 4; ++fr)
#pragma unroll
        for (int fc = 0; fc < 2; ++fc) {
          acc[fr][fc] = __builtin_amdgcn_mfma_f32_16x16x32_bf16(
              aH[fr], bH[fc], acc[fr][fc], 0, 0, 0);
          acc[fr][fc] = __builtin_amdgcn_mfma_f32_16x16x32_bf16(
              aH[fr], bL[fc], acc[fr][fc], 0, 0, 0);
        }
    }
  };

  auto zstage = [&](int c0) {
#pragma unroll
    for (int fc = 0; fc < 2; ++fc) {
      int col = cbase + fc * 16 + rl;
      unsigned int lc = (unsigned int)(col - c0);
      if (lc < 64u) {
        float bb = b1[col];
#pragma unroll
        for (int fr = 0; fr < 4; ++fr)
#pragma unroll
          for (int q = 0; q < 4; ++q) {
            int row = rbase + fr * 16 + g * 4 + q;
            float z = fmaxf(acc[fr][fc][q] + bb, 0.f);
            int off = row * 128 + (((lc >> 3) ^ (row & 7)) << 4) + (lc & 7) * 2;
            *(unsigned short*)((char*)As + off) = (unsigned short)bf16h(z);
          }
      }
    }
  };

  zacc();
  if (KIND == 0) {
    stageW(W1h, W1l, 0); stageAf(Af, 0);
    __syncthreads(); kloop(); __syncthreads();
    stageW(W1h, W1l, 1); stageAf(Af, 64);
    __syncthreads(); kloop();
  } else {
    stageW(W1h, W1l, 0); stageAb(Ab, 0);
    __syncthreads(); kloop(); __syncthreads();
    stageW(W1h, W1l, 1); stageAb(Ab, 64);
    __syncthreads(); kloop(); __syncthreads();
    stageW(W1h, W1l, 2); stageAb(A2b, 0);
    __syncthreads(); kloop(); __syncthreads();
    stageW(W1h, W1l, 3); stageAb(A2b, 64);
    __syncthreads(); kloop(); __syncthreads();

    stageW(W2h, W2l, 0); zstage(0);
    f32x4 acc1[4][2];
#pragma unroll
    for (int i = 0; i < 4; ++i)
#pragma unroll
      for (int j = 0; j < 2; ++j) acc1[i][j] = acc[i][j];
    zacc();
    __syncthreads(); kloop(); __syncthreads();
#pragma unroll
    for (int i = 0; i < 4; ++i)
#pragma unroll
      for (int j = 0; j < 2; ++j) {
        f32x4 tmp = acc[i][j];
        acc[i][j] = acc1[i][j];
        acc1[i][j] = tmp;
      }
    stageW(W2h, W2l, 1); zstage(64);
#pragma unroll
    for (int i = 0; i < 4; ++i)
#pragma unroll
      for (int j = 0; j < 2; ++j) acc[i][j] = acc1[i][j];
    __syncthreads(); kloop();
  }

  // ---- epilogue: stage C in LDS -> coalesced 16B/lane writes ---------------
  __syncthreads();
  unsigned short* Cs = lds;  // 32KB
  const float* bias = (KIND == 0) ? b1 : b2;
#pragma unroll
  for (int fc = 0; fc < 2; ++fc) {
    int col = cbase + fc * 16 + rl;
    float bb = bias[col];
#pragma unroll
    for (int fr = 0; fr < 4; ++fr)
#pragma unroll
      for (int q = 0; q < 4; ++q) {
        int row = rbase + fr * 16 + g * 4 + q;
        float val = acc[fr][fc][q] + bb;
        if (KIND == 1) val = fmaxf(val, 0.f);
        Cs[row * 128 + col] = (unsigned short)bf16h(val);
      }
  }
  __syncthreads();
#pragma unroll
  for (int p = 0; p < 4; ++p) {
    int bo = p * 8192 + t * 16;
    int row = bo >> 8;
    int grow = rowbase + row;
    if (grow >= M) continue;
    int4 z4 = *(const int4*)((const char*)Cs + bo);
    if (KIND == 1) {
      int4 a4 = *(const int4*)((const char*)Ab + (size_t)grow * 256 + (bo & 255));
      int* zp = (int*)&z4;
      const int* ap = (const int*)&a4;
#pragma unroll
      for (int u = 0; u < 4; ++u) {
        unsigned int za = (unsigned int)zp[u], aa = (unsigned int)ap[u];
        float vlo = b2f(za & 0xffffu) + b2f(aa & 0xffffu);
        float vhi = __uint_as_float(za & 0xffff0000u) +
                    __uint_as_float(aa & 0xffff0000u);
        zp[u] = (int)(bf16h(vlo) | (bf16h(vhi) << 16));
      }
    }
    *(int4*)((char*)outb + (size_t)grow * 256 + (bo & 255)) = z4;
  }
}

// ---------------------------------------------------------------------------
// Pooling + readout (h in bf16)
// ---------------------------------------------------------------------------
__global__ __launch_bounds__(256) void pool_partial(
    const unsigned short* __restrict__ h, float* __restrict__ partial, int N) {
  int col = threadIdx.x & 127;
  int stream = blockIdx.x * 2 + (threadIdx.x >> 7);
  float s = 0.f;
  for (int r = stream; r < N; r += 512)
    s += b2f((unsigned int)h[(size_t)r * 128 + col]);
  partial[stream * 128 + col] = s;
}

__global__ __launch_bounds__(256) void readout_kernel(
    const float* __restrict__ partial, const float* __restrict__ rW1,
    const float* __restrict__ rb1, const float* __restrict__ rW2,
    const float* __restrict__ rb2, const float* __restrict__ rW3,
    const float* __restrict__ rb3, float* __restrict__ outp, int N) {
  __shared__ float pooled[128];
  __shared__ float x1[64];
  __shared__ float x2[32];
  int t = threadIdx.x;
  if (t < 128) {
    float s = 0.f;
    for (int i = 0; i < 512; ++i) s += partial[i * 128 + t];
    pooled[t] = s / (float)N;
  }
  __syncthreads();
  if (t < 64) {
    float s = rb1[t];
    for (int k = 0; k < 128; ++k) s = fmaf(pooled[k], rW1[k * 64 + t], s);
    x1[t] = fmaxf(s, 0.f);
  }
  __syncthreads();
  if (t < 32) {
    float s = rb2[t];
    for (int k = 0; k < 64; ++k) s = fmaf(x1[k], rW2[k * 32 + t], s);
    x2[t] = fmaxf(s, 0.f);
  }
  __syncthreads();
  if (t < 10) {
    float s = rb3[t];
    for (int k = 0; k < 32; ++k) s = fmaf(x2[k], rW3[k * 10 + t], s);
    outp[t] = s;
  }
}

extern "C" void kernel_launch(void* const* d_in, const int* in_sizes, int n_in,
                              void* d_out, int out_size, void* d_ws, size_t ws_size,
                              hipStream_t stream) {
  const float* h_in  = (const float*)d_in[0];
  const int*   src   = (const int*)d_in[1];
  const int*   dst   = (const int*)d_in[2];
  const float* enc_W = (const float*)d_in[3];
  const float* enc_b = (const float*)d_in[4];
  const float* W1    = (const float*)d_in[5];
  const float* b1    = (const float*)d_in[6];
  const float* W2    = (const float*)d_in[7];
  const float* b2    = (const float*)d_in[8];
  const float* rW1   = (const float*)d_in[9];
  const float* rb1   = (const float*)d_in[10];
  const float* rW2   = (const float*)d_in[11];
  const float* rb2   = (const float*)d_in[12];
  const float* rW3   = (const float*)d_in[13];
  const float* rb3   = (const float*)d_in[14];

  const int N = in_sizes[0] / 128;
  const int E = in_sizes[1];
  const int L = in_sizes[6] / 128;
  const int NB = (N + 127) >> 7;
  const int chunk = (E + NBLK - 1) / NBLK;

  char* ws = (char*)d_ws;
  size_t off = 0;
  auto alloc = [&](size_t bytes) {
    char* p = ws + off;
    off = (off + bytes + 511) & ~(size_t)511;
    return p;
  };
  unsigned short* h   = (unsigned short*)alloc((size_t)N * 128 * 2);
  unsigned short* agg = (unsigned short*)alloc((size_t)N * 128 * 2);
  int* rowptr     = (int*)alloc((size_t)(N + 1) * 4);
  int* colidx     = (int*)alloc((size_t)E * 4);
  float* n1       = (float*)alloc((size_t)N * 4);
  float* n2       = (float*)alloc((size_t)N * 4);
  int* histG      = (int*)alloc((size_t)NB * NBLK * 4);
  int* bucketStart= (int*)alloc((size_t)(NB + 1) * 4);
  float* partial  = (float*)alloc((size_t)512 * 128 * 4);
  unsigned short* encWh = (unsigned short*)alloc(16384 * 2);
  unsigned short* encWl = (unsigned short*)alloc(16384 * 2);
  unsigned short* W1th  = (unsigned short*)alloc((size_t)L * 32768 * 2);
  unsigned short* W1tl  = (unsigned short*)alloc((size_t)L * 32768 * 2);
  unsigned short* W2th  = (unsigned short*)alloc((size_t)L * 16384 * 2);
  unsigned short* W2tl  = (unsigned short*)alloc((size_t)L * 16384 * 2);
  int2* pairs = (int2*)alloc((size_t)E * 8);   // CSR scratch (dead after bucketC)
  (void)ws_size; (void)n_in; (void)out_size;

  {
    int tot = 16384 + L * 32768 + L * 16384;
    prep_all<<<(tot + 255) / 256, 256, 0, stream>>>(
        enc_W, W1, W2, encWh, encWl, W1th, W1tl, W2th, W2tl, L);
  }

  bucketA<<<NBLK, 1024, 0, stream>>>(dst, histG, E, chunk, NB);
  bucketS<<<1, 1024, 0, stream>>>(histG, bucketStart, NB);
  bucketB<<<NBLK, 1024, 0, stream>>>(src, dst, histG, bucketStart, pairs, E,
                                     chunk, NB);
  bucketC<<<NB, 256, 0, stream>>>(pairs, bucketStart, rowptr, colidx, n1, n2, N, E);

  const int gblocks = (N + 127) / 128;
  sage_mm<0><<<gblocks, 512, 0, stream>>>(h_in, nullptr, nullptr, encWh, encWl,
                                          nullptr, nullptr, enc_b, nullptr, h, N);
  for (int l = 0; l < L; ++l) {
    agg_kernel<<<(N + 3) / 4, 256, 0, stream>>>(h, rowptr, colidx, n1, n2, agg, N);
    sage_mm<1><<<gblocks, 512, 0, stream>>>(
        nullptr, h, agg, W1th + (size_t)l * 32768, W1tl + (size_t)l * 32768,
        W2th + (size_t)l * 16384, W2tl + (size_t)l * 16384,
        b1 + l * 128, b2 + l * 128, h, N);
  }
  pool_partial<<<256, 256, 0, stream>>>(h, partial, N);
  readout_kernel<<<1, 256, 0, stream>>>(partial, rW1, rb1, rW2, rb2, rW3, rb3,
                                        (float*)d_out, N);
}